// Round 3
// baseline (688.174 us; speedup 1.0000x reference)
//
#include <hip/hip_runtime.h>
#include <hip/hip_bf16.h>
#include <stdint.h>

#define NNODES 100000
#define DF 64
#define NEDGES 1600000
#define ND (NNODES * DF)   // 6,400,000

// ---------- helpers ----------
static __device__ __forceinline__ float bf2f(unsigned short u) {
    union { uint32_t i; float f; } c; c.i = ((uint32_t)u) << 16; return c.f;
}
static __device__ __forceinline__ void unpack2(uint32_t u, float& lo, float& hi) {
    union { uint32_t i; float f; } a, b;
    a.i = u << 16; b.i = u & 0xFFFF0000u;
    lo = a.f; hi = b.f;
}

// Load one 64-feature row of x into xr[], honoring dtype flag.
static __device__ __forceinline__ void load_row(const void* xv, int bf, size_t node, float* xr) {
    if (bf) {
        const uint4* xp = (const uint4*)((const unsigned short*)xv + node * DF);
        #pragma unroll
        for (int t = 0; t < 8; ++t) {
            uint4 q = xp[t];
            unpack2(q.x, xr[8*t+0], xr[8*t+1]);
            unpack2(q.y, xr[8*t+2], xr[8*t+3]);
            unpack2(q.z, xr[8*t+4], xr[8*t+5]);
            unpack2(q.w, xr[8*t+6], xr[8*t+7]);
        }
    } else {
        const float4* xp = (const float4*)((const float*)xv + node * DF);
        #pragma unroll
        for (int t = 0; t < 16; ++t) {
            float4 q = xp[t];
            xr[4*t+0] = q.x; xr[4*t+1] = q.y; xr[4*t+2] = q.z; xr[4*t+3] = q.w;
        }
    }
}

// ---------- dtype detector ----------
// flags[0] = 1 if float tensors are bf16 (else fp32)
// flags[1] = 1 if edge_index is int64 (else int32)
__global__ void detect_k(const unsigned short* __restrict__ x,
                         const unsigned int* __restrict__ ei,
                         int* __restrict__ flags) {
    __shared__ int cnt_sane, cnt_odd_nz;
    if (threadIdx.x == 0) { cnt_sane = 0; cnt_odd_nz = 0; }
    __syncthreads();
    // even-indexed shorts: bf16 data -> sane exponents; fp32 data -> uniform mantissa bits
    unsigned short s = x[threadIdx.x * 2];
    unsigned short m = s & 0x7FFF;
    if (m < 0x0080 || (m >= 0x3000 && m <= 0x4200)) atomicAdd(&cnt_sane, 1);
    if (threadIdx.x < 64) {
        if (ei[threadIdx.x * 2 + 1] != 0u) atomicAdd(&cnt_odd_nz, 1);
    }
    __syncthreads();
    if (threadIdx.x == 0) {
        flags[0] = (cnt_sane >= 192) ? 1 : 0;
        flags[1] = (cnt_odd_nz == 0) ? 1 : 0;
    }
}

// ---------- weight/param canonicalization -> fp32 ----------
// WfM/WfU rows: [128][64]; row j<64 = W[:, :64] row j; row j>=64 = W[:, 64:] row (j-64)
// prm: [0:64) b_msg | [64:128) b_upd | [128:192) gamma | [192:256) beta
__global__ void wconv_k(const int* __restrict__ flags,
                        const void* __restrict__ Wm, const void* __restrict__ Wu,
                        const void* __restrict__ bm, const void* __restrict__ bu,
                        const void* __restrict__ ga, const void* __restrict__ be,
                        float* __restrict__ WfM, float* __restrict__ WfU,
                        float* __restrict__ prm) {
    const int bf = flags[0];
    int i = blockIdx.x * 256 + threadIdx.x;
    if (i < 16384) {
        const void* src = (i < 8192) ? Wm : Wu;
        float* dst = (i < 8192) ? WfM : WfU;
        int ii = i & 8191, j = ii >> 6, k = ii & 63;
        int si = (j & 63) * 128 + ((j >> 6) ? 64 : 0) + k;
        dst[ii] = bf ? bf2f(((const unsigned short*)src)[si]) : ((const float*)src)[si];
    } else if (i < 16384 + 256) {
        int t = i - 16384, which = t >> 6, k = t & 63;
        const void* p = (which == 0) ? bm : (which == 1) ? bu : (which == 2) ? ga : be;
        prm[t] = bf ? bf2f(((const unsigned short*)p)[k]) : ((const float*)p)[k];
    }
}

// ---------- projection: Ps = x @ Wm_s^T ; Pt = x @ Wm_t^T + b_msg (bf16 storage) ----------
__global__ __launch_bounds__(256) void proj_k(const int* __restrict__ flags,
                                              const void* __restrict__ xv,
                                              const float* __restrict__ WfM,
                                              const float* __restrict__ prm,
                                              __hip_bfloat16* __restrict__ Ps,
                                              __hip_bfloat16* __restrict__ Pt) {
    const int bf = flags[0];
    const int lane = threadIdx.x & 63;
    const int wib  = threadIdx.x >> 6;
    const int node = (blockIdx.x * 4 + wib) * 64 + lane;
    const int jbase = blockIdx.y * 32;

    float xr[64];
    if (node < NNODES) {
        load_row(xv, bf, (size_t)node, xr);
    } else {
        #pragma unroll
        for (int t = 0; t < 64; ++t) xr[t] = 0.f;
    }

    for (int j = jbase; j < jbase + 32; ++j) {
        const float* wr = WfM + j * 64;   // wave-uniform
        float a0 = 0.f, a1 = 0.f, a2 = 0.f, a3 = 0.f;
        #pragma unroll
        for (int k = 0; k < 64; k += 4) {
            a0 = fmaf(xr[k+0], wr[k+0], a0);
            a1 = fmaf(xr[k+1], wr[k+1], a1);
            a2 = fmaf(xr[k+2], wr[k+2], a2);
            a3 = fmaf(xr[k+3], wr[k+3], a3);
        }
        float acc = (a0 + a1) + (a2 + a3);
        if (node < NNODES) {
            if (j < 64) Ps[(size_t)node * DF + j] = __float2bfloat16(acc);
            else        Pt[(size_t)node * DF + (j - 64)] = __float2bfloat16(acc + prm[j - 64]);
        }
    }
}

// ---------- edge scatter (primary): msg = relu(Ps[src]+Pt[tgt]) ----------
__global__ __launch_bounds__(256) void edge_k(const int* __restrict__ flags,
                                              const int* __restrict__ ei,
                                              const __hip_bfloat16* __restrict__ Ps,
                                              const __hip_bfloat16* __restrict__ Pt,
                                              float* __restrict__ Msg,
                                              int* __restrict__ Cnt) {
    const int i64 = flags[1];
    const int lane = threadIdx.x & 63;
    const int wid  = (blockIdx.x * 256 + threadIdx.x) >> 6;
    const int nw   = (gridDim.x * 256) >> 6;
    for (int e = wid; e < NEDGES; e += nw) {
        int src, tgt;
        if (i64) { src = ei[4*e]; tgt = ei[4*e + 2]; }
        else     { int2 p = ((const int2*)ei)[e]; src = p.x; tgt = p.y; }
        if ((unsigned)src >= NNODES || (unsigned)tgt >= NNODES) continue;
        float v = __bfloat162float(Ps[(size_t)src * DF + lane])
                + __bfloat162float(Pt[(size_t)tgt * DF + lane]);
        v = fmaxf(v, 0.0f);
        if (v > 0.0f)
            atomicAdd(Msg + (size_t)tgt * DF + lane, v);
        if (lane == 0)
            atomicAdd(Cnt + tgt, 1);
    }
}

// ---------- edge direct (fallback for small ws): per-edge shuffle GEMV ----------
__global__ __launch_bounds__(256) void edge_direct_k(const int* __restrict__ flags,
                                                     const void* __restrict__ xv,
                                                     const int* __restrict__ ei,
                                                     const float* __restrict__ WfM,
                                                     const float* __restrict__ prm,
                                                     float* __restrict__ Msg,
                                                     int* __restrict__ Cnt) {
    const int bf = flags[0], i64 = flags[1];
    const int lane = threadIdx.x & 63;
    const int wid  = (blockIdx.x * 256 + threadIdx.x) >> 6;
    const int nw   = (gridDim.x * 256) >> 6;
    for (int e = wid; e < NEDGES; e += nw) {
        int src, tgt;
        if (i64) { src = ei[4*e]; tgt = ei[4*e + 2]; }
        else     { src = ei[2*e]; tgt = ei[2*e + 1]; }
        if ((unsigned)src >= NNODES || (unsigned)tgt >= NNODES) continue;
        float xs, xt;
        if (bf) { xs = bf2f(((const unsigned short*)xv)[(size_t)src * DF + lane]);
                  xt = bf2f(((const unsigned short*)xv)[(size_t)tgt * DF + lane]); }
        else    { xs = ((const float*)xv)[(size_t)src * DF + lane];
                  xt = ((const float*)xv)[(size_t)tgt * DF + lane]; }
        float acc = prm[lane];                      // b_msg[lane]
        const float* wsr = WfM + lane * 64;         // Wm_s[lane, :]
        const float* wtr = WfM + (lane + 64) * 64;  // Wm_t[lane, :]
        #pragma unroll 8
        for (int k = 0; k < 64; ++k) {
            float a = __shfl(xs, k, 64);
            float b = __shfl(xt, k, 64);
            acc = fmaf(a, wsr[k], acc);
            acc = fmaf(b, wtr[k], acc);
        }
        acc = fmaxf(acc, 0.0f);
        if (acc > 0.0f)
            atomicAdd(Msg + (size_t)tgt * DF + lane, acc);
        if (lane == 0)
            atomicAdd(Cnt + tgt, 1);
    }
}

// ---------- update + residual + LayerNorm ----------
__global__ __launch_bounds__(128) void upd_k(const int* __restrict__ flags,
                                             const void* __restrict__ xv,
                                             const float* __restrict__ Msg,
                                             const int* __restrict__ Cnt,
                                             const float* __restrict__ WfU,
                                             const float* __restrict__ prm,
                                             void* __restrict__ outv) {
    __shared__ float rbuf[64 * 129];
    __shared__ float mus[128], rss[128];
    const int bf = flags[0];
    const int tid = threadIdx.x;
    const int node = blockIdx.x * 128 + tid;

    float xr[64], mr[64];
    if (node < NNODES) {
        load_row(xv, bf, (size_t)node, xr);
        float inv = 1.0f / fmaxf((float)Cnt[node], 1.0f);
        const float4* mp = (const float4*)(Msg + (size_t)node * DF);
        #pragma unroll
        for (int t = 0; t < 16; ++t) {
            float4 m = mp[t];
            mr[4*t+0] = m.x * inv; mr[4*t+1] = m.y * inv;
            mr[4*t+2] = m.z * inv; mr[4*t+3] = m.w * inv;
        }
    } else {
        #pragma unroll
        for (int t = 0; t < 64; ++t) { xr[t] = 0.f; mr[t] = 0.f; }
    }

    float s = 0.f, s2 = 0.f;
    for (int j = 0; j < 64; ++j) {
        const float* wx = WfU + j * 64;
        const float* wm = WfU + (j + 64) * 64;
        float a0 = 0.f, a1 = 0.f, a2 = 0.f, a3 = 0.f;
        #pragma unroll
        for (int k = 0; k < 64; k += 2) {
            a0 = fmaf(xr[k],   wx[k],   a0);
            a1 = fmaf(xr[k+1], wx[k+1], a1);
            a2 = fmaf(mr[k],   wm[k],   a2);
            a3 = fmaf(mr[k+1], wm[k+1], a3);
        }
        float u = fmaxf((a0 + a1) + (a2 + a3) + prm[64 + j], 0.f);
        float xj = 0.f;
        if (node < NNODES)
            xj = bf ? bf2f(((const unsigned short*)xv)[(size_t)node * DF + j])
                    : ((const float*)xv)[(size_t)node * DF + j];
        float r = u + xj;
        rbuf[j * 129 + tid] = r;
        s += r;
        s2 = fmaf(r, r, s2);
    }
    float mu  = s * (1.0f / 64.0f);
    float var = fmaxf(s2 * (1.0f / 64.0f) - mu * mu, 0.f);
    mus[tid] = mu;
    rss[tid] = rsqrtf(var + 1e-5f);
    __syncthreads();

    const size_t base = (size_t)blockIdx.x * 128 * 64;
    for (int it = 0; it < 64; ++it) {
        int f  = it * 128 + tid;
        int nl = f >> 6;
        int j  = f & 63;
        size_t gi = base + (size_t)f;
        if (gi < (size_t)ND) {
            float r = rbuf[j * 129 + nl];
            float o = (r - mus[nl]) * rss[nl] * prm[128 + j] + prm[192 + j];
            if (bf) ((__hip_bfloat16*)outv)[gi] = __float2bfloat16(o);
            else    ((float*)outv)[gi] = o;
        }
    }
}

extern "C" void kernel_launch(void* const* d_in, const int* in_sizes, int n_in,
                              void* d_out, int out_size, void* d_ws, size_t ws_size,
                              hipStream_t stream) {
    const void* x  = d_in[0];
    const int*  ei = (const int*)d_in[1];
    const void* Wm = d_in[2];
    const void* bm = d_in[3];
    const void* Wu = d_in[4];
    const void* bu = d_in[5];
    const void* ga = d_in[6];
    const void* be = d_in[7];

    char* ws = (char*)d_ws;
    const bool primary = ws_size >= (size_t)51700000;

    size_t off = 0;
    __hip_bfloat16* Ps = nullptr;
    __hip_bfloat16* Pt = nullptr;
    if (primary) {
        Ps = (__hip_bfloat16*)ws;
        Pt = Ps + ND;
        off = (size_t)ND * 2 * 2;            // 25.6 MB of bf16 Ps|Pt
    }
    float* Msg = (float*)(ws + off);  off += (size_t)ND * 4;   // 25.6 MB
    float* WfM = (float*)(ws + off);  off += 8192 * 4;
    float* WfU = (float*)(ws + off);  off += 8192 * 4;
    float* prm = (float*)(ws + off);  off += 256 * 4;
    int*   Cnt = (int*)(ws + off);    off += (size_t)NNODES * 4;
    int*   flg = (int*)(ws + off);

    // zero Msg..Cnt (WfM/WfU/prm inside the range are overwritten by wconv_k)
    (void)hipMemsetAsync(Msg, 0, (size_t)ND * 4 + 8192 * 8 + 256 * 4 + (size_t)NNODES * 4, stream);

    detect_k<<<1, 256, 0, stream>>>((const unsigned short*)x, (const unsigned int*)ei, flg);
    wconv_k<<<65, 256, 0, stream>>>(flg, Wm, Wu, bm, bu, ga, be, WfM, WfU, prm);

    if (primary) {
        dim3 pg(391, 4);
        proj_k<<<pg, 256, 0, stream>>>(flg, x, WfM, prm, Ps, Pt);
        edge_k<<<4096, 256, 0, stream>>>(flg, ei, Ps, Pt, Msg, Cnt);
    } else {
        edge_direct_k<<<8192, 256, 0, stream>>>(flg, x, ei, WfM, prm, Msg, Cnt);
    }

    upd_k<<<(NNODES + 127) / 128, 128, 0, stream>>>(flg, x, Msg, Cnt, WfU, prm, d_out);
}